// Round 1
// baseline (838.797 us; speedup 1.0000x reference)
//
#include <hip/hip_runtime.h>
#include <stdint.h>
#include <stddef.h>

typedef __attribute__((ext_vector_type(4))) float floatx4;
typedef __attribute__((ext_vector_type(8))) int intx8;

#define T_TOK 16384
#define DM 1024
#define DF 4096
#define NE 8
#define CAP 2048

#define SCALE_ONE 127   // E8M0: 2^0
#define SCALE_W   121   // E8M0: 2^-6 (weights stored pre-scaled by 64)

// pack 4 fp32 -> 4 fp8 e4m3 (OCP) bytes in an int
static __device__ __forceinline__ int pk4(float a, float b, float c, float d) {
  int v = __builtin_amdgcn_cvt_pk_fp8_f32(a, b, 0, false);
  v = __builtin_amdgcn_cvt_pk_fp8_f32(c, d, v, true);
  return v;
}

// async global->LDS, 16 bytes per lane; LDS dest must be wave-uniform base + lane*16
static __device__ __forceinline__ void async_cp16(const void* g, void* l) {
  typedef const unsigned int __attribute__((address_space(1)))* gp_t;
  typedef unsigned int __attribute__((address_space(3)))* lp_t;
  __builtin_amdgcn_global_load_lds((gp_t)g, (lp_t)l, 16, 0, 0);
}

// ---------------------------------------------------------------- init
__global__ void init_kernel(int* __restrict__ src_token, float* __restrict__ stats) {
  int i = blockIdx.x * 256 + threadIdx.x;
  if (i < NE * CAP) src_token[i] = -1;
  if (i < 16) stats[i] = 0.f;
}

// ---------------------------------------------------------------- router (fp32, exact)
// De-spilled: w[4][4][8] (128 floats) held in VGPRs under __launch_bounds__(256,2)
// (budget 256 VGPR/lane; grid is only 2 waves/EU anyway so no occupancy cost).
// x loads vectorized to float4 and software-pipelined 1 token ahead.
__global__ void __launch_bounds__(256, 2) router_kernel(
    const float* __restrict__ x, const float* __restrict__ wr,
    int* __restrict__ top_idx, float* __restrict__ top_prob,
    float* __restrict__ stats) {
  int tid = threadIdx.x;
  int lane = tid & 63;
  int gw = (blockIdx.x * 256 + tid) >> 6;  // 2048 waves total

  // per-lane rows: r(i,c) = i*256 + lane*4 + c  (matches float4 x loads below)
  float w[4][4][8];
#pragma unroll
  for (int i = 0; i < 4; i++) {
#pragma unroll
    for (int c = 0; c < 4; c++) {
      const float4* p = (const float4*)&wr[(size_t)(i * 256 + lane * 4 + c) * 8];
      float4 a = p[0], b = p[1];
      w[i][c][0] = a.x; w[i][c][1] = a.y; w[i][c][2] = a.z; w[i][c][3] = a.w;
      w[i][c][4] = b.x; w[i][c][5] = b.y; w[i][c][6] = b.z; w[i][c][7] = b.w;
    }
  }

  float pi_acc[8] = {0, 0, 0, 0, 0, 0, 0, 0};
  float z_acc = 0.f;

  // prefetch first token
  float4 xa[4];
  {
    const float* xr = &x[(size_t)gw * DM];
#pragma unroll
    for (int i = 0; i < 4; i++)
      xa[i] = *(const float4*)&xr[i * 256 + lane * 4];
  }

  for (int t = gw; t < T_TOK; t += 2048) {
    // prefetch next token (clamped re-load of current on last iter: harmless, keeps flow simple)
    int tn = t + 2048;
    if (tn >= T_TOK) tn = t;
    const float* xrn = &x[(size_t)tn * DM];
    float4 xb[4];
#pragma unroll
    for (int i = 0; i < 4; i++)
      xb[i] = *(const float4*)&xrn[i * 256 + lane * 4];

    float acc[8] = {0, 0, 0, 0, 0, 0, 0, 0};
#pragma unroll
    for (int i = 0; i < 4; i++) {
#pragma unroll
      for (int c = 0; c < 4; c++) {
        float xv = xa[i][c];
#pragma unroll
        for (int e = 0; e < 8; e++) acc[e] = fmaf(xv, w[i][c][e], acc[e]);
      }
    }
#pragma unroll
    for (int off = 32; off > 0; off >>= 1) {
#pragma unroll
      for (int e = 0; e < 8; e++) acc[e] += __shfl_xor(acc[e], off, 64);
    }
    float mx = acc[0]; int mi = 0;
#pragma unroll
    for (int e = 1; e < 8; e++) { if (acc[e] > mx) { mx = acc[e]; mi = e; } }
    float s = 0.f, pr[8];
#pragma unroll
    for (int e = 0; e < 8; e++) { pr[e] = __expf(acc[e] - mx); s += pr[e]; }
    float inv = 1.f / s;
#pragma unroll
    for (int e = 0; e < 8; e++) pi_acc[e] += pr[e] * inv;
    float lse = mx + __logf(s);
    z_acc += lse * lse;
    if (lane == 0) { top_idx[t] = mi; top_prob[t] = pr[mi] * inv; }

#pragma unroll
    for (int i = 0; i < 4; i++) xa[i] = xb[i];
  }
  if (lane == 0) {
#pragma unroll
    for (int e = 0; e < 8; e++) atomicAdd(&stats[e], pi_acc[e]);
    atomicAdd(&stats[8], z_acc);
  }
}

// ---------------------------------------------------------------- FCFS scan
__global__ void __launch_bounds__(1024) scan_kernel(
    const int* __restrict__ top_idx, const float* __restrict__ stats,
    int* __restrict__ dest_slot, int* __restrict__ src_token,
    float* __restrict__ aux_out) {
  __shared__ int cnt[1024 * 9];
  int tid = threadIdx.x;
  int eloc[16];
  int c[8] = {0, 0, 0, 0, 0, 0, 0, 0};
#pragma unroll
  for (int i = 0; i < 16; i++) {
    int e = top_idx[tid * 16 + i];
    eloc[i] = e;
    c[e]++;
  }
#pragma unroll
  for (int e = 0; e < 8; e++) cnt[tid * 9 + e] = c[e];
  __syncthreads();
  for (int s = 1; s < 1024; s <<= 1) {
    int v[8];
    if (tid >= s) {
#pragma unroll
      for (int e = 0; e < 8; e++) v[e] = cnt[(tid - s) * 9 + e];
    }
    __syncthreads();
    if (tid >= s) {
#pragma unroll
      for (int e = 0; e < 8; e++) cnt[tid * 9 + e] += v[e];
    }
    __syncthreads();
  }
  int run[8];
#pragma unroll
  for (int e = 0; e < 8; e++) run[e] = cnt[tid * 9 + e] - c[e];
#pragma unroll
  for (int i = 0; i < 16; i++) {
    int t = tid * 16 + i;
    int e = eloc[i];
    int pos = run[e]++;
    int d = (pos < CAP) ? (e * CAP + pos) : -1;
    dest_slot[t] = d;
    if (d >= 0) src_token[d] = t;
  }
  if (tid == 1023) {
    float aux = 0.f;
    for (int e = 0; e < 8; e++)
      aux += ((float)cnt[1023 * 9 + e] / (float)T_TOK) * (stats[e] / (float)T_TOK);
    aux = 0.01f * 8.f * aux + 0.001f * (stats[8] / (float)T_TOK);
    *aux_out = aux;
  }
}

// ---------------------------------------------------------------- dispatch + cast fp8
__global__ void __launch_bounds__(256) dispatch_kernel(
    const float* __restrict__ x, const int* __restrict__ src_token,
    unsigned char* __restrict__ A) {
  int slot = blockIdx.x;
  int tid = threadIdx.x;
  int src = src_token[slot];
  int v = 0;
  if (src >= 0) {
    float4 xv = *(const float4*)&x[(size_t)src * DM + tid * 4];
    v = pk4(xv.x, xv.y, xv.z, xv.w);
  }
  *(int*)&A[(size_t)slot * DM + tid * 4] = v;
}

// ---------------------------------------------------------------- transpose + cast fp8 (x64)
// src fp32 [E][K][N] -> dst fp8 [E][N][K], values scaled by 64 (HW scale 2^-6 undoes it)
__global__ void __launch_bounds__(256) transpose_cast_kernel(
    const float* __restrict__ src, unsigned char* __restrict__ dst,
    int K, int N) {
  __shared__ float tile[64][65];
  int e = blockIdx.z;
  int n0 = blockIdx.x * 64, k0 = blockIdx.y * 64;
  int tid = threadIdx.x;
  int tx = tid & 63, ty = tid >> 6;
  const float* S = src + (size_t)e * K * N;
  unsigned char* D = dst + (size_t)e * N * K;
#pragma unroll
  for (int r = 0; r < 16; r++) {
    int k = ty + r * 4;
    tile[k][tx] = S[(size_t)(k0 + k) * N + n0 + tx];
  }
  __syncthreads();
  int n = tid >> 2, kq = (tid & 3) * 16;
  int4 ov;
  int w[4];
#pragma unroll
  for (int g = 0; g < 4; g++) {
    int kk = kq + g * 4;
    w[g] = pk4(tile[kk + 0][n] * 64.f, tile[kk + 1][n] * 64.f,
               tile[kk + 2][n] * 64.f, tile[kk + 3][n] * 64.f);
  }
  ov.x = w[0]; ov.y = w[1]; ov.z = w[2]; ov.w = w[3];
  *(int4*)&D[(size_t)(n0 + n) * K + k0 + kq] = ov;
}

// LDS chunk swizzle: 128-byte rows of 8x16B chunks; data chunk cc stored at cc ^ (row&7)
// -> fragment reads hit 2 lanes/bank (free), staging stays within one 128B segment/row.

// ---------------------------------------------------------------- GEMM1: H = relu(A @ w1 + b1) fp8 out
// A fp8 [E*CAP][DM], BT=W1T fp8x64 [E][DF][DM]
__global__ void __launch_bounds__(256) gemm1_kernel(
    const unsigned char* __restrict__ A, const unsigned char* __restrict__ BT,
    const float* __restrict__ b1, unsigned char* __restrict__ H) {
  __shared__ unsigned char As[128 * 128];
  __shared__ unsigned char Bs[128 * 128];
  int e = blockIdx.z;
  int n0 = blockIdx.x * 128, m0 = blockIdx.y * 128;
  const unsigned char* Ae = A + ((size_t)e * CAP + m0) * DM;
  const unsigned char* Be = BT + ((size_t)e * DF + n0) * DM;
  int tid = threadIdx.x;
  int lane = tid & 63, wid = tid >> 6;
  int wm = (wid & 1) * 64, wn = (wid >> 1) * 64;
  int l15 = lane & 15, q = lane >> 4;
  floatx4 acc[4][4];
#pragma unroll
  for (int i = 0; i < 4; i++)
#pragma unroll
    for (int j = 0; j < 4; j++) acc[i][j] = (floatx4){0.f, 0.f, 0.f, 0.f};
  for (int kb = 0; kb < DM; kb += 128) {
#pragma unroll
    for (int r = 0; r < 4; r++) {
      int c = tid + 256 * r;
      int row = c >> 3, cc = c & 7;
      int ccs = cc ^ (row & 7);
      async_cp16(Ae + (size_t)row * DM + kb + ccs * 16, As + c * 16);
      async_cp16(Be + (size_t)row * DM + kb + ccs * 16, Bs + c * 16);
    }
    __syncthreads();
    intx8 af[4], bf[4];
#pragma unroll
    for (int i = 0; i < 4; i++) {
      int row = wm + i * 16 + l15;
      int sw = row & 7;
      int4 lo = *(const int4*)&As[row * 128 + ((2 * q) ^ sw) * 16];
      int4 hi = *(const int4*)&As[row * 128 + ((2 * q + 1) ^ sw) * 16];
      af[i] = (intx8){lo.x, lo.y, lo.z, lo.w, hi.x, hi.y, hi.z, hi.w};
    }
#pragma unroll
    for (int j = 0; j < 4; j++) {
      int row = wn + j * 16 + l15;
      int sw = row & 7;
      int4 lo = *(const int4*)&Bs[row * 128 + ((2 * q) ^ sw) * 16];
      int4 hi = *(const int4*)&Bs[row * 128 + ((2 * q + 1) ^ sw) * 16];
      bf[j] = (intx8){lo.x, lo.y, lo.z, lo.w, hi.x, hi.y, hi.z, hi.w};
    }
#pragma unroll
    for (int i = 0; i < 4; i++)
#pragma unroll
      for (int j = 0; j < 4; j++)
        acc[i][j] = __builtin_amdgcn_mfma_scale_f32_16x16x128_f8f6f4(
            bf[j], af[i], acc[i][j], 0, 0, 0, SCALE_W, 0, SCALE_ONE);
    __syncthreads();
  }
  // operand-swap => D: m = l15, n = q*4 + reg
  const float* b1e = b1 + e * DF;
#pragma unroll
  for (int i = 0; i < 4; i++) {
    int m = m0 + wm + i * 16 + l15;
    unsigned char* hrow = H + ((size_t)e * CAP + m) * DF;
#pragma unroll
    for (int j = 0; j < 4; j++) {
      int nb = n0 + wn + j * 16 + q * 4;
      float4 bv = *(const float4*)&b1e[nb];
      floatx4 a = acc[i][j];
      *(int*)&hrow[nb] = pk4(fmaxf(a[0] + bv.x, 0.f), fmaxf(a[1] + bv.y, 0.f),
                             fmaxf(a[2] + bv.z, 0.f), fmaxf(a[3] + bv.w, 0.f));
    }
  }
}

// ---------------------------------------------------------------- GEMM2: out[t] = p*(H @ w2 + b2)
// Hm fp8 [E][CAP][DF], BT=W2T fp8x64 [E][DM][DF]
__global__ void __launch_bounds__(256) gemm2_kernel(
    const unsigned char* __restrict__ Hm, const unsigned char* __restrict__ BT,
    const float* __restrict__ b2, const int* __restrict__ src_token,
    const float* __restrict__ top_prob, float* __restrict__ out) {
  __shared__ unsigned char As[128 * 128];
  __shared__ unsigned char Bs[128 * 128];
  int e = blockIdx.z;
  int n0 = blockIdx.x * 128, m0 = blockIdx.y * 128;
  const unsigned char* Ae = Hm + ((size_t)e * CAP + m0) * DF;
  const unsigned char* Be = BT + ((size_t)e * DM + n0) * DF;
  int tid = threadIdx.x;
  int lane = tid & 63, wid = tid >> 6;
  int wm = (wid & 1) * 64, wn = (wid >> 1) * 64;
  int l15 = lane & 15, q = lane >> 4;
  floatx4 acc[4][4];
#pragma unroll
  for (int i = 0; i < 4; i++)
#pragma unroll
    for (int j = 0; j < 4; j++) acc[i][j] = (floatx4){0.f, 0.f, 0.f, 0.f};
  for (int kb = 0; kb < DF; kb += 128) {
#pragma unroll
    for (int r = 0; r < 4; r++) {
      int c = tid + 256 * r;
      int row = c >> 3, cc = c & 7;
      int ccs = cc ^ (row & 7);
      async_cp16(Ae + (size_t)row * DF + kb + ccs * 16, As + c * 16);
      async_cp16(Be + (size_t)row * DF + kb + ccs * 16, Bs + c * 16);
    }
    __syncthreads();
    intx8 af[4], bf[4];
#pragma unroll
    for (int i = 0; i < 4; i++) {
      int row = wm + i * 16 + l15;
      int sw = row & 7;
      int4 lo = *(const int4*)&As[row * 128 + ((2 * q) ^ sw) * 16];
      int4 hi = *(const int4*)&As[row * 128 + ((2 * q + 1) ^ sw) * 16];
      af[i] = (intx8){lo.x, lo.y, lo.z, lo.w, hi.x, hi.y, hi.z, hi.w};
    }
#pragma unroll
    for (int j = 0; j < 4; j++) {
      int row = wn + j * 16 + l15;
      int sw = row & 7;
      int4 lo = *(const int4*)&Bs[row * 128 + ((2 * q) ^ sw) * 16];
      int4 hi = *(const int4*)&Bs[row * 128 + ((2 * q + 1) ^ sw) * 16];
      bf[j] = (intx8){lo.x, lo.y, lo.z, lo.w, hi.x, hi.y, hi.z, hi.w};
    }
#pragma unroll
    for (int i = 0; i < 4; i++)
#pragma unroll
      for (int j = 0; j < 4; j++)
        acc[i][j] = __builtin_amdgcn_mfma_scale_f32_16x16x128_f8f6f4(
            bf[j], af[i], acc[i][j], 0, 0, 0, SCALE_W, 0, SCALE_ONE);
    __syncthreads();
  }
  const float* b2e = b2 + e * DM;
#pragma unroll
  for (int i = 0; i < 4; i++) {
    int m = m0 + wm + i * 16 + l15;
    int t = src_token[e * CAP + m];
    if (t < 0) continue;
    float p = top_prob[t];
    float* orow = out + (size_t)t * DM;
#pragma unroll
    for (int j = 0; j < 4; j++) {
      int nb = n0 + wn + j * 16 + q * 4;
      float4 bv = *(const float4*)&b2e[nb];
      floatx4 a = acc[i][j];
      float4 o;
      o.x = p * (a[0] + bv.x);
      o.y = p * (a[1] + bv.y);
      o.z = p * (a[2] + bv.z);
      o.w = p * (a[3] + bv.w);
      *(float4*)&orow[nb] = o;
    }
  }
}

// ---------------------------------------------------------------- dropped-token passthrough
__global__ void __launch_bounds__(256) passthru_kernel(
    const float* __restrict__ x, const int* __restrict__ dest_slot,
    float* __restrict__ out) {
  int t = blockIdx.x;
  if (dest_slot[t] >= 0) return;
  int c = threadIdx.x * 4;
  *(float4*)&out[(size_t)t * DM + c] = *(const float4*)&x[(size_t)t * DM + c];
}

// ---------------------------------------------------------------- launch
extern "C" void kernel_launch(void* const* d_in, const int* in_sizes, int n_in,
                              void* d_out, int out_size, void* d_ws, size_t ws_size,
                              hipStream_t stream) {
  const float* x  = (const float*)d_in[0];
  const float* wr = (const float*)d_in[1];
  const float* w1 = (const float*)d_in[2];
  const float* b1 = (const float*)d_in[3];
  const float* w2 = (const float*)d_in[4];
  const float* b2 = (const float*)d_in[5];
  float* out = (float*)d_out;

  // workspace layout (bytes)
  const size_t OFF_A    = 0;             // 16,777,216  A fp8 [E*CAP][DM]
  const size_t OFF_W1T  = 16777216;      // 33,554,432  W1T fp8 [E][DF][DM]
  const size_t OFF_W2T  = 50331648;      // 33,554,432  W2T fp8 [E][DM][DF]
  const size_t OFF_H    = 83886080;      // 67,108,864  H fp8 [E][CAP][DF]
  const size_t OFF_TIDX = 150994944;
  const size_t OFF_TPRB = 151060480;
  const size_t OFF_DEST = 151126016;
  const size_t OFF_SRC  = 151191552;
  const size_t OFF_STAT = 151257088;
  if (ws_size < OFF_STAT + 64) return;

  char* ws = (char*)d_ws;
  unsigned char* A_f8 = (unsigned char*)(ws + OFF_A);
  unsigned char* W1T  = (unsigned char*)(ws + OFF_W1T);
  unsigned char* W2T  = (unsigned char*)(ws + OFF_W2T);
  unsigned char* Hbuf = (unsigned char*)(ws + OFF_H);
  int*   top_idx   = (int*)(ws + OFF_TIDX);
  float* top_prob  = (float*)(ws + OFF_TPRB);
  int*   dest_slot = (int*)(ws + OFF_DEST);
  int*   src_token = (int*)(ws + OFF_SRC);
  float* stats     = (float*)(ws + OFF_STAT);

  hipLaunchKernelGGL(init_kernel, dim3(64), dim3(256), 0, stream, src_token, stats);
  hipLaunchKernelGGL(router_kernel, dim3(512), dim3(256), 0, stream,
                     x, wr, top_idx, top_prob, stats);
  hipLaunchKernelGGL(scan_kernel, dim3(1), dim3(1024), 0, stream,
                     top_idx, stats, dest_slot, src_token, out + (size_t)T_TOK * DM);
  hipLaunchKernelGGL(dispatch_kernel, dim3(NE * CAP), dim3(256), 0, stream,
                     x, src_token, A_f8);
  hipLaunchKernelGGL(transpose_cast_kernel, dim3(DF / 64, DM / 64, NE), dim3(256), 0, stream,
                     w1, W1T, DM, DF);
  hipLaunchKernelGGL(transpose_cast_kernel, dim3(DM / 64, DF / 64, NE), dim3(256), 0, stream,
                     w2, W2T, DF, DM);
  hipLaunchKernelGGL(gemm1_kernel, dim3(DF / 128, CAP / 128, NE), dim3(256), 0, stream,
                     A_f8, W1T, b1, Hbuf);
  hipLaunchKernelGGL(gemm2_kernel, dim3(DM / 128, CAP / 128, NE), dim3(256), 0, stream,
                     Hbuf, W2T, b2, src_token, top_prob, out);
  hipLaunchKernelGGL(passthru_kernel, dim3(T_TOK), dim3(256), 0, stream,
                     x, dest_slot, out);
}

// Round 2
// 638.569 us; speedup vs baseline: 1.3136x; 1.3136x over previous
//
#include <hip/hip_runtime.h>
#include <stdint.h>
#include <stddef.h>

typedef __attribute__((ext_vector_type(4))) float floatx4;
typedef __attribute__((ext_vector_type(8))) int intx8;

#define T_TOK 16384
#define DM 1024
#define DF 4096
#define NE 8
#define CAP 2048

#define SCALE_ONE 127   // E8M0: 2^0
#define SCALE_W   121   // E8M0: 2^-6 (weights stored pre-scaled by 64)

// pack 4 fp32 -> 4 fp8 e4m3 (OCP) bytes in an int
static __device__ __forceinline__ int pk4(float a, float b, float c, float d) {
  int v = __builtin_amdgcn_cvt_pk_fp8_f32(a, b, 0, false);
  v = __builtin_amdgcn_cvt_pk_fp8_f32(c, d, v, true);
  return v;
}

// async global->LDS, 16 bytes per lane; LDS dest must be wave-uniform base + lane*16
static __device__ __forceinline__ void async_cp16(const void* g, void* l) {
  typedef const unsigned int __attribute__((address_space(1)))* gp_t;
  typedef unsigned int __attribute__((address_space(3)))* lp_t;
  __builtin_amdgcn_global_load_lds((gp_t)g, (lp_t)l, 16, 0, 0);
}

// ---------------------------------------------------------------- init
__global__ void init_kernel(int* __restrict__ src_token) {
  int i = blockIdx.x * 256 + threadIdx.x;
  if (i < NE * CAP) src_token[i] = -1;
}

// ---------------------------------------------------------------- router (fp32, exact)
// Weights LDS-resident (32 KB), conflict-free ds_read_b128; no global atomics:
// per-block pi/z partials go to part[block][16] (A_f8 region, overwritten later
// by dispatch_kernel which runs after scan_kernel consumed the partials).
__global__ void __launch_bounds__(256, 4) router_kernel(
    const float* __restrict__ x, const float* __restrict__ wr,
    int* __restrict__ top_idx, float* __restrict__ top_prob,
    float* __restrict__ part) {
  __shared__ float wl[8][1024];      // [expert][feature]
  __shared__ float bstat[4][12];
  int tid = threadIdx.x;
  int lane = tid & 63, w = tid >> 6;

  // stage wr [1024][8] -> wl[8][1024] (transposed), coalesced float4 reads
#pragma unroll
  for (int r = 0; r < 8; r++) {
    int j = tid + 256 * r;           // float4 index into flat wr (2048 total)
    float4 v = ((const float4*)wr)[j];
    int f = j >> 1;
    int e0 = (j & 1) * 4;
    wl[e0 + 0][f] = v.x;
    wl[e0 + 1][f] = v.y;
    wl[e0 + 2][f] = v.z;
    wl[e0 + 3][f] = v.w;
  }
  __syncthreads();

  int t0 = blockIdx.x * 8 + w * 2;   // 2 tokens per wave

  // load both tokens' x up front (16 B per lane per i-block)
  float4 xa[2][4];
#pragma unroll
  for (int tok = 0; tok < 2; tok++)
#pragma unroll
    for (int i = 0; i < 4; i++)
      xa[tok][i] = *(const float4*)&x[(size_t)(t0 + tok) * DM + i * 256 + lane * 4];

  float acc[2][8];
#pragma unroll
  for (int tok = 0; tok < 2; tok++)
#pragma unroll
    for (int e = 0; e < 8; e++) acc[tok][e] = 0.f;

#pragma unroll
  for (int i = 0; i < 4; i++) {
    float4 wv[8];
#pragma unroll
    for (int e = 0; e < 8; e++)
      wv[e] = *(const float4*)&wl[e][i * 256 + lane * 4];
#pragma unroll
    for (int tok = 0; tok < 2; tok++) {
      float4 xv = xa[tok][i];
#pragma unroll
      for (int e = 0; e < 8; e++)
        acc[tok][e] = fmaf(xv.x, wv[e].x,
                      fmaf(xv.y, wv[e].y,
                      fmaf(xv.z, wv[e].z,
                      fmaf(xv.w, wv[e].w, acc[tok][e]))));
    }
  }

  float pi_acc[8] = {0, 0, 0, 0, 0, 0, 0, 0};
  float z_acc = 0.f;
#pragma unroll
  for (int tok = 0; tok < 2; tok++) {
    float a[8];
#pragma unroll
    for (int e = 0; e < 8; e++) a[e] = acc[tok][e];
#pragma unroll
    for (int off = 32; off > 0; off >>= 1)
#pragma unroll
      for (int e = 0; e < 8; e++) a[e] += __shfl_xor(a[e], off, 64);
    float mx = a[0]; int mi = 0;
#pragma unroll
    for (int e = 1; e < 8; e++) { if (a[e] > mx) { mx = a[e]; mi = e; } }
    float s = 0.f, pr[8];
#pragma unroll
    for (int e = 0; e < 8; e++) { pr[e] = __expf(a[e] - mx); s += pr[e]; }
    float inv = 1.f / s;
#pragma unroll
    for (int e = 0; e < 8; e++) pi_acc[e] += pr[e] * inv;
    float lse = mx + __logf(s);
    z_acc += lse * lse;
    if (lane == 0) { top_idx[t0 + tok] = mi; top_prob[t0 + tok] = pr[mi] * inv; }
  }

  // per-block stats partial (no global atomics)
  if (lane == 0) {
#pragma unroll
    for (int e = 0; e < 8; e++) bstat[w][e] = pi_acc[e];
    bstat[w][8] = z_acc;
  }
  __syncthreads();
  if (tid < 9) {
    float s = bstat[0][tid] + bstat[1][tid] + bstat[2][tid] + bstat[3][tid];
    part[(size_t)blockIdx.x * 16 + tid] = s;
  }
}

// ---------------------------------------------------------------- FCFS scan (+stats reduce)
__global__ void __launch_bounds__(1024) scan_kernel(
    const int* __restrict__ top_idx, const float* __restrict__ part,
    int* __restrict__ dest_slot, int* __restrict__ src_token,
    float* __restrict__ aux_out) {
  __shared__ int cnt[1024 * 9];
  __shared__ float sstat[16][12];
  int tid = threadIdx.x;

  // reduce 2048 per-block router partials (9 floats each)
  float ps[9];
#pragma unroll
  for (int e = 0; e < 9; e++) ps[e] = 0.f;
#pragma unroll
  for (int rr = 0; rr < 2; rr++) {
    const float* pp = &part[(size_t)(tid + rr * 1024) * 16];
#pragma unroll
    for (int e = 0; e < 9; e++) ps[e] += pp[e];
  }
#pragma unroll
  for (int off = 32; off > 0; off >>= 1)
#pragma unroll
    for (int e = 0; e < 9; e++) ps[e] += __shfl_xor(ps[e], off, 64);
  if ((tid & 63) == 0) {
#pragma unroll
    for (int e = 0; e < 9; e++) sstat[tid >> 6][e] = ps[e];
  }

  int eloc[16];
  int c[8] = {0, 0, 0, 0, 0, 0, 0, 0};
#pragma unroll
  for (int i = 0; i < 16; i++) {
    int e = top_idx[tid * 16 + i];
    eloc[i] = e;
    c[e]++;
  }
#pragma unroll
  for (int e = 0; e < 8; e++) cnt[tid * 9 + e] = c[e];
  __syncthreads();
  for (int s = 1; s < 1024; s <<= 1) {
    int v[8];
    if (tid >= s) {
#pragma unroll
      for (int e = 0; e < 8; e++) v[e] = cnt[(tid - s) * 9 + e];
    }
    __syncthreads();
    if (tid >= s) {
#pragma unroll
      for (int e = 0; e < 8; e++) cnt[tid * 9 + e] += v[e];
    }
    __syncthreads();
  }
  int run[8];
#pragma unroll
  for (int e = 0; e < 8; e++) run[e] = cnt[tid * 9 + e] - c[e];
#pragma unroll
  for (int i = 0; i < 16; i++) {
    int t = tid * 16 + i;
    int e = eloc[i];
    int pos = run[e]++;
    int d = (pos < CAP) ? (e * CAP + pos) : -1;
    dest_slot[t] = d;
    if (d >= 0) src_token[d] = t;
  }
  if (tid == 1023) {
    float st[9];
#pragma unroll
    for (int e = 0; e < 9; e++) {
      float s = 0.f;
      for (int ww = 0; ww < 16; ww++) s += sstat[ww][e];
      st[e] = s;
    }
    float aux = 0.f;
    for (int e = 0; e < 8; e++)
      aux += ((float)cnt[1023 * 9 + e] / (float)T_TOK) * (st[e] / (float)T_TOK);
    aux = 0.01f * 8.f * aux + 0.001f * (st[8] / (float)T_TOK);
    *aux_out = aux;
  }
}

// ---------------------------------------------------------------- dispatch + cast fp8
__global__ void __launch_bounds__(256) dispatch_kernel(
    const float* __restrict__ x, const int* __restrict__ src_token,
    unsigned char* __restrict__ A) {
  int slot = blockIdx.x;
  int tid = threadIdx.x;
  int src = src_token[slot];
  int v = 0;
  if (src >= 0) {
    float4 xv = *(const float4*)&x[(size_t)src * DM + tid * 4];
    v = pk4(xv.x, xv.y, xv.z, xv.w);
  }
  *(int*)&A[(size_t)slot * DM + tid * 4] = v;
}

// ---------------------------------------------------------------- transpose + cast fp8 (x64)
// src fp32 [E][K][N] -> dst fp8 [E][N][K], values scaled by 64 (HW scale 2^-6 undoes it)
__global__ void __launch_bounds__(256) transpose_cast_kernel(
    const float* __restrict__ src, unsigned char* __restrict__ dst,
    int K, int N) {
  __shared__ float tile[64][65];
  int e = blockIdx.z;
  int n0 = blockIdx.x * 64, k0 = blockIdx.y * 64;
  int tid = threadIdx.x;
  int tx = tid & 63, ty = tid >> 6;
  const float* S = src + (size_t)e * K * N;
  unsigned char* D = dst + (size_t)e * N * K;
#pragma unroll
  for (int r = 0; r < 16; r++) {
    int k = ty + r * 4;
    tile[k][tx] = S[(size_t)(k0 + k) * N + n0 + tx];
  }
  __syncthreads();
  int n = tid >> 2, kq = (tid & 3) * 16;
  int4 ov;
  int w[4];
#pragma unroll
  for (int g = 0; g < 4; g++) {
    int kk = kq + g * 4;
    w[g] = pk4(tile[kk + 0][n] * 64.f, tile[kk + 1][n] * 64.f,
               tile[kk + 2][n] * 64.f, tile[kk + 3][n] * 64.f);
  }
  ov.x = w[0]; ov.y = w[1]; ov.z = w[2]; ov.w = w[3];
  *(int4*)&D[(size_t)(n0 + n) * K + k0 + kq] = ov;
}

// LDS chunk swizzle: 128-byte rows of 8x16B chunks; data chunk cc stored at cc ^ (row&7)
// -> fragment reads hit 2 lanes/bank (free), staging stays within one 128B segment/row.

// ---------------------------------------------------------------- GEMM1: H = relu(A @ w1 + b1) fp8 out
// A fp8 [E*CAP][DM], BT=W1T fp8x64 [E][DF][DM]
__global__ void __launch_bounds__(256) gemm1_kernel(
    const unsigned char* __restrict__ A, const unsigned char* __restrict__ BT,
    const float* __restrict__ b1, unsigned char* __restrict__ H) {
  __shared__ unsigned char As[128 * 128];
  __shared__ unsigned char Bs[128 * 128];
  int e = blockIdx.z;
  int n0 = blockIdx.x * 128, m0 = blockIdx.y * 128;
  const unsigned char* Ae = A + ((size_t)e * CAP + m0) * DM;
  const unsigned char* Be = BT + ((size_t)e * DF + n0) * DM;
  int tid = threadIdx.x;
  int lane = tid & 63, wid = tid >> 6;
  int wm = (wid & 1) * 64, wn = (wid >> 1) * 64;
  int l15 = lane & 15, q = lane >> 4;
  floatx4 acc[4][4];
#pragma unroll
  for (int i = 0; i < 4; i++)
#pragma unroll
    for (int j = 0; j < 4; j++) acc[i][j] = (floatx4){0.f, 0.f, 0.f, 0.f};
  for (int kb = 0; kb < DM; kb += 128) {
#pragma unroll
    for (int r = 0; r < 4; r++) {
      int c = tid + 256 * r;
      int row = c >> 3, cc = c & 7;
      int ccs = cc ^ (row & 7);
      async_cp16(Ae + (size_t)row * DM + kb + ccs * 16, As + c * 16);
      async_cp16(Be + (size_t)row * DM + kb + ccs * 16, Bs + c * 16);
    }
    __syncthreads();
    intx8 af[4], bf[4];
#pragma unroll
    for (int i = 0; i < 4; i++) {
      int row = wm + i * 16 + l15;
      int sw = row & 7;
      int4 lo = *(const int4*)&As[row * 128 + ((2 * q) ^ sw) * 16];
      int4 hi = *(const int4*)&As[row * 128 + ((2 * q + 1) ^ sw) * 16];
      af[i] = (intx8){lo.x, lo.y, lo.z, lo.w, hi.x, hi.y, hi.z, hi.w};
    }
#pragma unroll
    for (int j = 0; j < 4; j++) {
      int row = wn + j * 16 + l15;
      int sw = row & 7;
      int4 lo = *(const int4*)&Bs[row * 128 + ((2 * q) ^ sw) * 16];
      int4 hi = *(const int4*)&Bs[row * 128 + ((2 * q + 1) ^ sw) * 16];
      bf[j] = (intx8){lo.x, lo.y, lo.z, lo.w, hi.x, hi.y, hi.z, hi.w};
    }
#pragma unroll
    for (int i = 0; i < 4; i++)
#pragma unroll
      for (int j = 0; j < 4; j++)
        acc[i][j] = __builtin_amdgcn_mfma_scale_f32_16x16x128_f8f6f4(
            bf[j], af[i], acc[i][j], 0, 0, 0, SCALE_W, 0, SCALE_ONE);
    __syncthreads();
  }
  // operand-swap => D: m = l15, n = q*4 + reg
  const float* b1e = b1 + e * DF;
#pragma unroll
  for (int i = 0; i < 4; i++) {
    int m = m0 + wm + i * 16 + l15;
    unsigned char* hrow = H + ((size_t)e * CAP + m) * DF;
#pragma unroll
    for (int j = 0; j < 4; j++) {
      int nb = n0 + wn + j * 16 + q * 4;
      float4 bv = *(const float4*)&b1e[nb];
      floatx4 a = acc[i][j];
      *(int*)&hrow[nb] = pk4(fmaxf(a[0] + bv.x, 0.f), fmaxf(a[1] + bv.y, 0.f),
                             fmaxf(a[2] + bv.z, 0.f), fmaxf(a[3] + bv.w, 0.f));
    }
  }
}

// ---------------------------------------------------------------- GEMM2: out[t] = p*(H @ w2 + b2)
// Hm fp8 [E][CAP][DF], BT=W2T fp8x64 [E][DM][DF]
__global__ void __launch_bounds__(256) gemm2_kernel(
    const unsigned char* __restrict__ Hm, const unsigned char* __restrict__ BT,
    const float* __restrict__ b2, const int* __restrict__ src_token,
    const float* __restrict__ top_prob, float* __restrict__ out) {
  __shared__ unsigned char As[128 * 128];
  __shared__ unsigned char Bs[128 * 128];
  int e = blockIdx.z;
  int n0 = blockIdx.x * 128, m0 = blockIdx.y * 128;
  const unsigned char* Ae = Hm + ((size_t)e * CAP + m0) * DF;
  const unsigned char* Be = BT + ((size_t)e * DM + n0) * DF;
  int tid = threadIdx.x;
  int lane = tid & 63, wid = tid >> 6;
  int wm = (wid & 1) * 64, wn = (wid >> 1) * 64;
  int l15 = lane & 15, q = lane >> 4;
  floatx4 acc[4][4];
#pragma unroll
  for (int i = 0; i < 4; i++)
#pragma unroll
    for (int j = 0; j < 4; j++) acc[i][j] = (floatx4){0.f, 0.f, 0.f, 0.f};
  for (int kb = 0; kb < DF; kb += 128) {
#pragma unroll
    for (int r = 0; r < 4; r++) {
      int c = tid + 256 * r;
      int row = c >> 3, cc = c & 7;
      int ccs = cc ^ (row & 7);
      async_cp16(Ae + (size_t)row * DF + kb + ccs * 16, As + c * 16);
      async_cp16(Be + (size_t)row * DF + kb + ccs * 16, Bs + c * 16);
    }
    __syncthreads();
    intx8 af[4], bf[4];
#pragma unroll
    for (int i = 0; i < 4; i++) {
      int row = wm + i * 16 + l15;
      int sw = row & 7;
      int4 lo = *(const int4*)&As[row * 128 + ((2 * q) ^ sw) * 16];
      int4 hi = *(const int4*)&As[row * 128 + ((2 * q + 1) ^ sw) * 16];
      af[i] = (intx8){lo.x, lo.y, lo.z, lo.w, hi.x, hi.y, hi.z, hi.w};
    }
#pragma unroll
    for (int j = 0; j < 4; j++) {
      int row = wn + j * 16 + l15;
      int sw = row & 7;
      int4 lo = *(const int4*)&Bs[row * 128 + ((2 * q) ^ sw) * 16];
      int4 hi = *(const int4*)&Bs[row * 128 + ((2 * q + 1) ^ sw) * 16];
      bf[j] = (intx8){lo.x, lo.y, lo.z, lo.w, hi.x, hi.y, hi.z, hi.w};
    }
#pragma unroll
    for (int i = 0; i < 4; i++)
#pragma unroll
      for (int j = 0; j < 4; j++)
        acc[i][j] = __builtin_amdgcn_mfma_scale_f32_16x16x128_f8f6f4(
            bf[j], af[i], acc[i][j], 0, 0, 0, SCALE_W, 0, SCALE_ONE);
    __syncthreads();
  }
  const float* b2e = b2 + e * DM;
#pragma unroll
  for (int i = 0; i < 4; i++) {
    int m = m0 + wm + i * 16 + l15;
    int t = src_token[e * CAP + m];
    if (t < 0) continue;
    float p = top_prob[t];
    float* orow = out + (size_t)t * DM;
#pragma unroll
    for (int j = 0; j < 4; j++) {
      int nb = n0 + wn + j * 16 + q * 4;
      float4 bv = *(const float4*)&b2e[nb];
      floatx4 a = acc[i][j];
      float4 o;
      o.x = p * (a[0] + bv.x);
      o.y = p * (a[1] + bv.y);
      o.z = p * (a[2] + bv.z);
      o.w = p * (a[3] + bv.w);
      *(float4*)&orow[nb] = o;
    }
  }
}

// ---------------------------------------------------------------- dropped-token passthrough
__global__ void __launch_bounds__(256) passthru_kernel(
    const float* __restrict__ x, const int* __restrict__ dest_slot,
    float* __restrict__ out) {
  int t = blockIdx.x;
  if (dest_slot[t] >= 0) return;
  int c = threadIdx.x * 4;
  *(float4*)&out[(size_t)t * DM + c] = *(const float4*)&x[(size_t)t * DM + c];
}

// ---------------------------------------------------------------- launch
extern "C" void kernel_launch(void* const* d_in, const int* in_sizes, int n_in,
                              void* d_out, int out_size, void* d_ws, size_t ws_size,
                              hipStream_t stream) {
  const float* x  = (const float*)d_in[0];
  const float* wr = (const float*)d_in[1];
  const float* w1 = (const float*)d_in[2];
  const float* b1 = (const float*)d_in[3];
  const float* w2 = (const float*)d_in[4];
  const float* b2 = (const float*)d_in[5];
  float* out = (float*)d_out;

  // workspace layout (bytes)
  const size_t OFF_A    = 0;             // 16,777,216  A fp8 [E*CAP][DM]; router partials live here first
  const size_t OFF_W1T  = 16777216;      // 33,554,432  W1T fp8 [E][DF][DM]
  const size_t OFF_W2T  = 50331648;      // 33,554,432  W2T fp8 [E][DM][DF]
  const size_t OFF_H    = 83886080;      // 67,108,864  H fp8 [E][CAP][DF]
  const size_t OFF_TIDX = 150994944;
  const size_t OFF_TPRB = 151060480;
  const size_t OFF_DEST = 151126016;
  const size_t OFF_SRC  = 151191552;
  const size_t OFF_STAT = 151257088;
  if (ws_size < OFF_STAT + 64) return;

  char* ws = (char*)d_ws;
  unsigned char* A_f8 = (unsigned char*)(ws + OFF_A);
  float* part = (float*)(ws + OFF_A);    // 2048 blocks x 16 floats = 128 KB, consumed by scan before dispatch overwrites
  unsigned char* W1T  = (unsigned char*)(ws + OFF_W1T);
  unsigned char* W2T  = (unsigned char*)(ws + OFF_W2T);
  unsigned char* Hbuf = (unsigned char*)(ws + OFF_H);
  int*   top_idx   = (int*)(ws + OFF_TIDX);
  float* top_prob  = (float*)(ws + OFF_TPRB);
  int*   dest_slot = (int*)(ws + OFF_DEST);
  int*   src_token = (int*)(ws + OFF_SRC);

  hipLaunchKernelGGL(init_kernel, dim3(64), dim3(256), 0, stream, src_token);
  hipLaunchKernelGGL(router_kernel, dim3(2048), dim3(256), 0, stream,
                     x, wr, top_idx, top_prob, part);
  hipLaunchKernelGGL(scan_kernel, dim3(1), dim3(1024), 0, stream,
                     top_idx, part, dest_slot, src_token, out + (size_t)T_TOK * DM);
  hipLaunchKernelGGL(dispatch_kernel, dim3(NE * CAP), dim3(256), 0, stream,
                     x, src_token, A_f8);
  hipLaunchKernelGGL(transpose_cast_kernel, dim3(DF / 64, DM / 64, NE), dim3(256), 0, stream,
                     w1, W1T, DM, DF);
  hipLaunchKernelGGL(transpose_cast_kernel, dim3(DM / 64, DF / 64, NE), dim3(256), 0, stream,
                     w2, W2T, DF, DM);
  hipLaunchKernelGGL(gemm1_kernel, dim3(DF / 128, CAP / 128, NE), dim3(256), 0, stream,
                     A_f8, W1T, b1, Hbuf);
  hipLaunchKernelGGL(gemm2_kernel, dim3(DM / 128, CAP / 128, NE), dim3(256), 0, stream,
                     Hbuf, W2T, b2, src_token, top_prob, out);
  hipLaunchKernelGGL(passthru_kernel, dim3(T_TOK), dim3(256), 0, stream,
                     x, dest_slot, out);
}

// Round 4
// 626.337 us; speedup vs baseline: 1.3392x; 1.0195x over previous
//
#include <hip/hip_runtime.h>
#include <stdint.h>
#include <stddef.h>

typedef __attribute__((ext_vector_type(4))) float floatx4;
typedef __attribute__((ext_vector_type(8))) int intx8;

#define T_TOK 16384
#define DM 1024
#define DF 4096
#define NE 8
#define CAP 2048

#define SCALE_ONE 127   // E8M0: 2^0
#define SCALE_W   121   // E8M0: 2^-6 (weights stored pre-scaled by 64)

// pack 4 fp32 -> 4 fp8 e4m3 (OCP) bytes in an int
static __device__ __forceinline__ int pk4(float a, float b, float c, float d) {
  int v = __builtin_amdgcn_cvt_pk_fp8_f32(a, b, 0, false);
  v = __builtin_amdgcn_cvt_pk_fp8_f32(c, d, v, true);
  return v;
}

// async global->LDS, 16 bytes per lane; LDS dest must be wave-uniform base + lane*16
static __device__ __forceinline__ void async_cp16(const void* g, void* l) {
  typedef const unsigned int __attribute__((address_space(1)))* gp_t;
  typedef unsigned int __attribute__((address_space(3)))* lp_t;
  __builtin_amdgcn_global_load_lds((gp_t)g, (lp_t)l, 16, 0, 0);
}

// ---------------------------------------------------------------- init
__global__ void init_kernel(int* __restrict__ src_token) {
  int i = blockIdx.x * 256 + threadIdx.x;
  if (i < NE * CAP) src_token[i] = -1;
}

// ---------------------------------------------------------------- router (fp32, exact)
__global__ void __launch_bounds__(256, 4) router_kernel(
    const float* __restrict__ x, const float* __restrict__ wr,
    int* __restrict__ top_idx, float* __restrict__ top_prob,
    float* __restrict__ part) {
  __shared__ float wl[8][1024];      // [expert][feature]
  __shared__ float bstat[4][12];
  int tid = threadIdx.x;
  int lane = tid & 63, w = tid >> 6;

#pragma unroll
  for (int r = 0; r < 8; r++) {
    int j = tid + 256 * r;
    float4 v = ((const float4*)wr)[j];
    int f = j >> 1;
    int e0 = (j & 1) * 4;
    wl[e0 + 0][f] = v.x;
    wl[e0 + 1][f] = v.y;
    wl[e0 + 2][f] = v.z;
    wl[e0 + 3][f] = v.w;
  }
  __syncthreads();

  int t0 = blockIdx.x * 8 + w * 2;

  float4 xa[2][4];
#pragma unroll
  for (int tok = 0; tok < 2; tok++)
#pragma unroll
    for (int i = 0; i < 4; i++)
      xa[tok][i] = *(const float4*)&x[(size_t)(t0 + tok) * DM + i * 256 + lane * 4];

  float acc[2][8];
#pragma unroll
  for (int tok = 0; tok < 2; tok++)
#pragma unroll
    for (int e = 0; e < 8; e++) acc[tok][e] = 0.f;

#pragma unroll
  for (int i = 0; i < 4; i++) {
    float4 wv[8];
#pragma unroll
    for (int e = 0; e < 8; e++)
      wv[e] = *(const float4*)&wl[e][i * 256 + lane * 4];
#pragma unroll
    for (int tok = 0; tok < 2; tok++) {
      float4 xv = xa[tok][i];
#pragma unroll
      for (int e = 0; e < 8; e++)
        acc[tok][e] = fmaf(xv.x, wv[e].x,
                      fmaf(xv.y, wv[e].y,
                      fmaf(xv.z, wv[e].z,
                      fmaf(xv.w, wv[e].w, acc[tok][e]))));
    }
  }

  float pi_acc[8] = {0, 0, 0, 0, 0, 0, 0, 0};
  float z_acc = 0.f;
#pragma unroll
  for (int tok = 0; tok < 2; tok++) {
    float a[8];
#pragma unroll
    for (int e = 0; e < 8; e++) a[e] = acc[tok][e];
#pragma unroll
    for (int off = 32; off > 0; off >>= 1)
#pragma unroll
      for (int e = 0; e < 8; e++) a[e] += __shfl_xor(a[e], off, 64);
    float mx = a[0]; int mi = 0;
#pragma unroll
    for (int e = 1; e < 8; e++) { if (a[e] > mx) { mx = a[e]; mi = e; } }
    float s = 0.f, pr[8];
#pragma unroll
    for (int e = 0; e < 8; e++) { pr[e] = __expf(a[e] - mx); s += pr[e]; }
    float inv = 1.f / s;
#pragma unroll
    for (int e = 0; e < 8; e++) pi_acc[e] += pr[e] * inv;
    float lse = mx + __logf(s);
    z_acc += lse * lse;
    if (lane == 0) { top_idx[t0 + tok] = mi; top_prob[t0 + tok] = pr[mi] * inv; }
  }

  if (lane == 0) {
#pragma unroll
    for (int e = 0; e < 8; e++) bstat[w][e] = pi_acc[e];
    bstat[w][8] = z_acc;
  }
  __syncthreads();
  if (tid < 9) {
    float s = bstat[0][tid] + bstat[1][tid] + bstat[2][tid] + bstat[3][tid];
    part[(size_t)blockIdx.x * 16 + tid] = s;
  }
}

// ---------------------------------------------------------------- FCFS scan (+stats reduce)
__global__ void __launch_bounds__(1024) scan_kernel(
    const int* __restrict__ top_idx, const float* __restrict__ part,
    int* __restrict__ dest_slot, int* __restrict__ src_token,
    float* __restrict__ aux_out) {
  __shared__ int cnt[1024 * 9];
  __shared__ float sstat[16][12];
  int tid = threadIdx.x;

  float ps[9];
#pragma unroll
  for (int e = 0; e < 9; e++) ps[e] = 0.f;
#pragma unroll
  for (int rr = 0; rr < 2; rr++) {
    const float* pp = &part[(size_t)(tid + rr * 1024) * 16];
#pragma unroll
    for (int e = 0; e < 9; e++) ps[e] += pp[e];
  }
#pragma unroll
  for (int off = 32; off > 0; off >>= 1)
#pragma unroll
    for (int e = 0; e < 9; e++) ps[e] += __shfl_xor(ps[e], off, 64);
  if ((tid & 63) == 0) {
#pragma unroll
    for (int e = 0; e < 9; e++) sstat[tid >> 6][e] = ps[e];
  }

  int eloc[16];
  int c[8] = {0, 0, 0, 0, 0, 0, 0, 0};
#pragma unroll
  for (int i = 0; i < 16; i++) {
    int e = top_idx[tid * 16 + i];
    eloc[i] = e;
    c[e]++;
  }
#pragma unroll
  for (int e = 0; e < 8; e++) cnt[tid * 9 + e] = c[e];
  __syncthreads();
  for (int s = 1; s < 1024; s <<= 1) {
    int v[8];
    if (tid >= s) {
#pragma unroll
      for (int e = 0; e < 8; e++) v[e] = cnt[(tid - s) * 9 + e];
    }
    __syncthreads();
    if (tid >= s) {
#pragma unroll
      for (int e = 0; e < 8; e++) cnt[tid * 9 + e] += v[e];
    }
    __syncthreads();
  }
  int run[8];
#pragma unroll
  for (int e = 0; e < 8; e++) run[e] = cnt[tid * 9 + e] - c[e];
#pragma unroll
  for (int i = 0; i < 16; i++) {
    int t = tid * 16 + i;
    int e = eloc[i];
    int pos = run[e]++;
    int d = (pos < CAP) ? (e * CAP + pos) : -1;
    dest_slot[t] = d;
    if (d >= 0) src_token[d] = t;
  }
  if (tid == 1023) {
    float st[9];
#pragma unroll
    for (int e = 0; e < 9; e++) {
      float s = 0.f;
      for (int ww = 0; ww < 16; ww++) s += sstat[ww][e];
      st[e] = s;
    }
    float aux = 0.f;
    for (int e = 0; e < 8; e++)
      aux += ((float)cnt[1023 * 9 + e] / (float)T_TOK) * (st[e] / (float)T_TOK);
    aux = 0.01f * 8.f * aux + 0.001f * (st[8] / (float)T_TOK);
    *aux_out = aux;
  }
}

// ---------------------------------------------------------------- dispatch + cast fp8
__global__ void __launch_bounds__(256) dispatch_kernel(
    const float* __restrict__ x, const int* __restrict__ src_token,
    unsigned char* __restrict__ A) {
  int slot = blockIdx.x;
  int tid = threadIdx.x;
  int src = src_token[slot];
  int v = 0;
  if (src >= 0) {
    float4 xv = *(const float4*)&x[(size_t)src * DM + tid * 4];
    v = pk4(xv.x, xv.y, xv.z, xv.w);
  }
  *(int*)&A[(size_t)slot * DM + tid * 4] = v;
}

// ---------------------------------------------------------------- transpose + cast fp8 (x64)
// src fp32 [E][K][N] -> dst fp8 [E][N][K], values scaled by 64 (HW scale 2^-6 undoes it)
__global__ void __launch_bounds__(256) transpose_cast_kernel(
    const float* __restrict__ src, unsigned char* __restrict__ dst,
    int K, int N) {
  __shared__ float tile[64][65];
  int e = blockIdx.z;
  int n0 = blockIdx.x * 64, k0 = blockIdx.y * 64;
  int tid = threadIdx.x;
  int tx = tid & 63, ty = tid >> 6;
  const float* S = src + (size_t)e * K * N;
  unsigned char* D = dst + (size_t)e * N * K;
#pragma unroll
  for (int r = 0; r < 16; r++) {
    int k = ty + r * 4;
    tile[k][tx] = S[(size_t)(k0 + k) * N + n0 + tx];
  }
  __syncthreads();
  int n = tid >> 2, kq = (tid & 3) * 16;
  int4 ov;
  int w[4];
#pragma unroll
  for (int g = 0; g < 4; g++) {
    int kk = kq + g * 4;
    w[g] = pk4(tile[kk + 0][n] * 64.f, tile[kk + 1][n] * 64.f,
               tile[kk + 2][n] * 64.f, tile[kk + 3][n] * 64.f);
  }
  ov.x = w[0]; ov.y = w[1]; ov.z = w[2]; ov.w = w[3];
  *(int4*)&D[(size_t)(n0 + n) * K + k0 + kq] = ov;
}

// LDS chunk swizzle: 128-byte rows of 8x16B chunks; data chunk cc stored at cc ^ (row&7)
// -> fragment reads hit 2 lanes/bank (free), staging stays within one 128B segment/row.

// ---------------------------------------------------------------- GEMM1: H = relu(A @ w1 + b1) fp8 out
// 256x256 tile, 8 waves (2Mx4N), BK=128B, SINGLE-buffered LDS (64 KiB),
// round-2-verified sync structure: stage -> sync -> compute -> sync.
// A fp8 [E*CAP][DM], BT=W1T fp8x64 [E][DF][DM]
__global__ void __launch_bounds__(512, 2) gemm1_kernel(
    const unsigned char* __restrict__ A, const unsigned char* __restrict__ BT,
    const float* __restrict__ b1, unsigned char* __restrict__ H) {
  __shared__ __align__(16) unsigned char As[256 * 128];
  __shared__ __align__(16) unsigned char Bs[256 * 128];
  int e = blockIdx.z;
  // bijective XCD swizzle within the 16x8 per-expert plane (128 blocks, %8==0)
  int plane = blockIdx.x + 16 * blockIdx.y;
  int nid = (plane & 7) * 16 + (plane >> 3);
  int n0 = (nid & 15) * 256, m0 = (nid >> 4) * 256;
  const unsigned char* Ae = A + ((size_t)e * CAP + m0) * DM;
  const unsigned char* Be = BT + ((size_t)e * DF + n0) * DM;
  int tid = threadIdx.x;
  int lane = tid & 63, wid = tid >> 6;
  int wmi = wid >> 2, wni = wid & 3;   // wave -> 128x64 output subtile
  int l15 = lane & 15, q = lane >> 4;
  floatx4 acc[8][4];
#pragma unroll
  for (int i = 0; i < 8; i++)
#pragma unroll
    for (int j = 0; j < 4; j++) acc[i][j] = (floatx4){0.f, 0.f, 0.f, 0.f};

  for (int kb = 0; kb < DM; kb += 128) {
#pragma unroll
    for (int r = 0; r < 4; r++) {
      int c = tid + 512 * r;
      int row = c >> 3, cc = c & 7;
      int ccs = cc ^ (row & 7);
      async_cp16(Ae + (size_t)row * DM + kb + ccs * 16, As + c * 16);
      async_cp16(Be + (size_t)row * DM + kb + ccs * 16, Bs + c * 16);
    }
    __syncthreads();
#pragma unroll
    for (int ph = 0; ph < 4; ph++) {
      const int Mh = ph >> 1, Nh = ph & 1;
      intx8 af[4], bf[2];
#pragma unroll
      for (int i = 0; i < 4; i++) {
        int row = wmi * 128 + (Mh * 4 + i) * 16 + l15;
        int sw = row & 7;
        int4 lo = *(const int4*)&As[row * 128 + ((2 * q) ^ sw) * 16];
        int4 hi = *(const int4*)&As[row * 128 + ((2 * q + 1) ^ sw) * 16];
        af[i] = (intx8){lo.x, lo.y, lo.z, lo.w, hi.x, hi.y, hi.z, hi.w};
      }
#pragma unroll
      for (int j = 0; j < 2; j++) {
        int row = wni * 64 + (Nh * 2 + j) * 16 + l15;
        int sw = row & 7;
        int4 lo = *(const int4*)&Bs[row * 128 + ((2 * q) ^ sw) * 16];
        int4 hi = *(const int4*)&Bs[row * 128 + ((2 * q + 1) ^ sw) * 16];
        bf[j] = (intx8){lo.x, lo.y, lo.z, lo.w, hi.x, hi.y, hi.z, hi.w};
      }
#pragma unroll
      for (int i = 0; i < 4; i++)
#pragma unroll
        for (int j = 0; j < 2; j++)
          acc[Mh * 4 + i][Nh * 2 + j] = __builtin_amdgcn_mfma_scale_f32_16x16x128_f8f6f4(
              bf[j], af[i], acc[Mh * 4 + i][Nh * 2 + j], 0, 0, 0, SCALE_W, 0, SCALE_ONE);
    }
    __syncthreads();
  }
  // operand-swap => D: m = l15, n = q*4 + reg
  const float* b1e = b1 + e * DF;
#pragma unroll
  for (int i = 0; i < 8; i++) {
    int m = m0 + wmi * 128 + i * 16 + l15;
    unsigned char* hrow = H + ((size_t)e * CAP + m) * DF;
#pragma unroll
    for (int j = 0; j < 4; j++) {
      int nb = n0 + wni * 64 + j * 16 + q * 4;
      float4 bv = *(const float4*)&b1e[nb];
      floatx4 a = acc[i][j];
      *(int*)&hrow[nb] = pk4(fmaxf(a[0] + bv.x, 0.f), fmaxf(a[1] + bv.y, 0.f),
                             fmaxf(a[2] + bv.z, 0.f), fmaxf(a[3] + bv.w, 0.f));
    }
  }
}

// ---------------------------------------------------------------- GEMM2: out[t] = p*(H @ w2 + b2)
// same 256x256 single-buffered schedule; Hm fp8 [E][CAP][DF], BT=W2T fp8x64 [E][DM][DF]
__global__ void __launch_bounds__(512, 2) gemm2_kernel(
    const unsigned char* __restrict__ Hm, const unsigned char* __restrict__ BT,
    const float* __restrict__ b2, const int* __restrict__ src_token,
    const float* __restrict__ top_prob, float* __restrict__ out) {
  __shared__ __align__(16) unsigned char As[256 * 128];
  __shared__ __align__(16) unsigned char Bs[256 * 128];
  int e = blockIdx.z;
  // bijective XCD swizzle within the 4x8 per-expert plane (32 blocks, %8==0)
  int plane = blockIdx.x + 4 * blockIdx.y;
  int nid = (plane & 7) * 4 + (plane >> 3);
  int n0 = (nid & 3) * 256, m0 = (nid >> 2) * 256;
  const unsigned char* Ae = Hm + ((size_t)e * CAP + m0) * DF;
  const unsigned char* Be = BT + ((size_t)e * DM + n0) * DF;
  int tid = threadIdx.x;
  int lane = tid & 63, wid = tid >> 6;
  int wmi = wid >> 2, wni = wid & 3;
  int l15 = lane & 15, q = lane >> 4;
  floatx4 acc[8][4];
#pragma unroll
  for (int i = 0; i < 8; i++)
#pragma unroll
    for (int j = 0; j < 4; j++) acc[i][j] = (floatx4){0.f, 0.f, 0.f, 0.f};

  for (int kb = 0; kb < DF; kb += 128) {
#pragma unroll
    for (int r = 0; r < 4; r++) {
      int c = tid + 512 * r;
      int row = c >> 3, cc = c & 7;
      int ccs = cc ^ (row & 7);
      async_cp16(Ae + (size_t)row * DF + kb + ccs * 16, As + c * 16);
      async_cp16(Be + (size_t)row * DF + kb + ccs * 16, Bs + c * 16);
    }
    __syncthreads();
#pragma unroll
    for (int ph = 0; ph < 4; ph++) {
      const int Mh = ph >> 1, Nh = ph & 1;
      intx8 af[4], bf[2];
#pragma unroll
      for (int i = 0; i < 4; i++) {
        int row = wmi * 128 + (Mh * 4 + i) * 16 + l15;
        int sw = row & 7;
        int4 lo = *(const int4*)&As[row * 128 + ((2 * q) ^ sw) * 16];
        int4 hi = *(const int4*)&As[row * 128 + ((2 * q + 1) ^ sw) * 16];
        af[i] = (intx8){lo.x, lo.y, lo.z, lo.w, hi.x, hi.y, hi.z, hi.w};
      }
#pragma unroll
      for (int j = 0; j < 2; j++) {
        int row = wni * 64 + (Nh * 2 + j) * 16 + l15;
        int sw = row & 7;
        int4 lo = *(const int4*)&Bs[row * 128 + ((2 * q) ^ sw) * 16];
        int4 hi = *(const int4*)&Bs[row * 128 + ((2 * q + 1) ^ sw) * 16];
        bf[j] = (intx8){lo.x, lo.y, lo.z, lo.w, hi.x, hi.y, hi.z, hi.w};
      }
#pragma unroll
      for (int i = 0; i < 4; i++)
#pragma unroll
        for (int j = 0; j < 2; j++)
          acc[Mh * 4 + i][Nh * 2 + j] = __builtin_amdgcn_mfma_scale_f32_16x16x128_f8f6f4(
              bf[j], af[i], acc[Mh * 4 + i][Nh * 2 + j], 0, 0, 0, SCALE_W, 0, SCALE_ONE);
    }
    __syncthreads();
  }
  const float* b2e = b2 + e * DM;
#pragma unroll
  for (int i = 0; i < 8; i++) {
    int m = m0 + wmi * 128 + i * 16 + l15;
    int t = src_token[e * CAP + m];
    if (t < 0) continue;
    float p = top_prob[t];
    float* orow = out + (size_t)t * DM;
#pragma unroll
    for (int j = 0; j < 4; j++) {
      int nb = n0 + wni * 64 + j * 16 + q * 4;
      float4 bv = *(const float4*)&b2e[nb];
      floatx4 a = acc[i][j];
      float4 o;
      o.x = p * (a[0] + bv.x);
      o.y = p * (a[1] + bv.y);
      o.z = p * (a[2] + bv.z);
      o.w = p * (a[3] + bv.w);
      *(float4*)&orow[nb] = o;
    }
  }
}

// ---------------------------------------------------------------- dropped-token passthrough
__global__ void __launch_bounds__(256) passthru_kernel(
    const float* __restrict__ x, const int* __restrict__ dest_slot,
    float* __restrict__ out) {
  int t = blockIdx.x;
  if (dest_slot[t] >= 0) return;
  int c = threadIdx.x * 4;
  *(float4*)&out[(size_t)t * DM + c] = *(const float4*)&x[(size_t)t * DM + c];
}

// ---------------------------------------------------------------- launch
extern "C" void kernel_launch(void* const* d_in, const int* in_sizes, int n_in,
                              void* d_out, int out_size, void* d_ws, size_t ws_size,
                              hipStream_t stream) {
  const float* x  = (const float*)d_in[0];
  const float* wr = (const float*)d_in[1];
  const float* w1 = (const float*)d_in[2];
  const float* b1 = (const float*)d_in[3];
  const float* w2 = (const float*)d_in[4];
  const float* b2 = (const float*)d_in[5];
  float* out = (float*)d_out;

  // workspace layout (bytes)
  const size_t OFF_A    = 0;             // 16,777,216  A fp8 [E*CAP][DM]; router partials live here first
  const size_t OFF_W1T  = 16777216;      // 33,554,432  W1T fp8 [E][DF][DM]
  const size_t OFF_W2T  = 50331648;      // 33,554,432  W2T fp8 [E][DM][DF]
  const size_t OFF_H    = 83886080;      // 67,108,864  H fp8 [E][CAP][DF]
  const size_t OFF_TIDX = 150994944;
  const size_t OFF_TPRB = 151060480;
  const size_t OFF_DEST = 151126016;
  const size_t OFF_SRC  = 151191552;
  const size_t OFF_STAT = 151257088;
  if (ws_size < OFF_STAT + 64) return;

  char* ws = (char*)d_ws;
  unsigned char* A_f8 = (unsigned char*)(ws + OFF_A);
  float* part = (float*)(ws + OFF_A);    // 2048 blocks x 16 floats = 128 KB, consumed by scan before dispatch overwrites
  unsigned char* W1T  = (unsigned char*)(ws + OFF_W1T);
  unsigned char* W2T  = (unsigned char*)(ws + OFF_W2T);
  unsigned char* Hbuf = (unsigned char*)(ws + OFF_H);
  int*   top_idx   = (int*)(ws + OFF_TIDX);
  float* top_prob  = (float*)(ws + OFF_TPRB);
  int*   dest_slot = (int*)(ws + OFF_DEST);
  int*   src_token = (int*)(ws + OFF_SRC);

  hipLaunchKernelGGL(init_kernel, dim3(64), dim3(256), 0, stream, src_token);
  hipLaunchKernelGGL(router_kernel, dim3(2048), dim3(256), 0, stream,
                     x, wr, top_idx, top_prob, part);
  hipLaunchKernelGGL(scan_kernel, dim3(1), dim3(1024), 0, stream,
                     top_idx, part, dest_slot, src_token, out + (size_t)T_TOK * DM);
  hipLaunchKernelGGL(dispatch_kernel, dim3(NE * CAP), dim3(256), 0, stream,
                     x, src_token, A_f8);
  hipLaunchKernelGGL(transpose_cast_kernel, dim3(DF / 64, DM / 64, NE), dim3(256), 0, stream,
                     w1, W1T, DM, DF);
  hipLaunchKernelGGL(transpose_cast_kernel, dim3(DM / 64, DF / 64, NE), dim3(256), 0, stream,
                     w2, W2T, DF, DM);
  hipLaunchKernelGGL(gemm1_kernel, dim3(DF / 256, CAP / 256, NE), dim3(512), 0, stream,
                     A_f8, W1T, b1, Hbuf);
  hipLaunchKernelGGL(gemm2_kernel, dim3(DM / 256, CAP / 256, NE), dim3(512), 0, stream,
                     Hbuf, W2T, b2, src_token, top_prob, out);
  hipLaunchKernelGGL(passthru_kernel, dim3(T_TOK), dim3(256), 0, stream,
                     x, dest_slot, out);
}

// Round 7
// 615.777 us; speedup vs baseline: 1.3622x; 1.0171x over previous
//
#include <hip/hip_runtime.h>
#include <stdint.h>
#include <stddef.h>

typedef __attribute__((ext_vector_type(4))) float floatx4;
typedef __attribute__((ext_vector_type(8))) int intx8;

#define T_TOK 16384
#define DM 1024
#define DF 4096
#define NE 8
#define CAP 2048

#define SCALE_ONE 127   // E8M0: 2^0
#define SCALE_W   121   // E8M0: 2^-6 (weights stored pre-scaled by 64)

// pack 4 fp32 -> 4 fp8 e4m3 (OCP) bytes in an int
static __device__ __forceinline__ int pk4(float a, float b, float c, float d) {
  int v = __builtin_amdgcn_cvt_pk_fp8_f32(a, b, 0, false);
  v = __builtin_amdgcn_cvt_pk_fp8_f32(c, d, v, true);
  return v;
}

// async global->LDS, 16 bytes per lane; LDS dest must be wave-uniform base + lane*16
static __device__ __forceinline__ void async_cp16(const void* g, void* l) {
  typedef const unsigned int __attribute__((address_space(1)))* gp_t;
  typedef unsigned int __attribute__((address_space(3)))* lp_t;
  __builtin_amdgcn_global_load_lds((gp_t)g, (lp_t)l, 16, 0, 0);
}

// explicit per-wave drain of outstanding global_load_lds BEFORE the barrier.
// Cross-wave correctness of DMA staging requires drain-before-barrier; relying
// on __syncthreads' implicit wait raced (round 3 NaN). T3 recipe: vmcnt(0); barrier.
static __device__ __forceinline__ void drain_and_sync() {
  asm volatile("s_waitcnt vmcnt(0)" ::: "memory");
  __builtin_amdgcn_sched_barrier(0);
  __syncthreads();
}

// ---------------------------------------------------------------- init
__global__ void init_kernel(int* __restrict__ src_token) {
  int i = blockIdx.x * 256 + threadIdx.x;
  if (i < NE * CAP) src_token[i] = -1;
}

// ---------------------------------------------------------------- router (fp32, exact)
__global__ void __launch_bounds__(256, 4) router_kernel(
    const float* __restrict__ x, const float* __restrict__ wr,
    int* __restrict__ top_idx, float* __restrict__ top_prob,
    float* __restrict__ part) {
  __shared__ float wl[8][1024];      // [expert][feature]
  __shared__ float bstat[4][12];
  int tid = threadIdx.x;
  int lane = tid & 63, w = tid >> 6;

#pragma unroll
  for (int r = 0; r < 8; r++) {
    int j = tid + 256 * r;
    float4 v = ((const float4*)wr)[j];
    int f = j >> 1;
    int e0 = (j & 1) * 4;
    wl[e0 + 0][f] = v.x;
    wl[e0 + 1][f] = v.y;
    wl[e0 + 2][f] = v.z;
    wl[e0 + 3][f] = v.w;
  }
  __syncthreads();

  int t0 = blockIdx.x * 8 + w * 2;

  float4 xa[2][4];
#pragma unroll
  for (int tok = 0; tok < 2; tok++)
#pragma unroll
    for (int i = 0; i < 4; i++)
      xa[tok][i] = *(const float4*)&x[(size_t)(t0 + tok) * DM + i * 256 + lane * 4];

  float acc[2][8];
#pragma unroll
  for (int tok = 0; tok < 2; tok++)
#pragma unroll
    for (int e = 0; e < 8; e++) acc[tok][e] = 0.f;

#pragma unroll
  for (int i = 0; i < 4; i++) {
    float4 wv[8];
#pragma unroll
    for (int e = 0; e < 8; e++)
      wv[e] = *(const float4*)&wl[e][i * 256 + lane * 4];
#pragma unroll
    for (int tok = 0; tok < 2; tok++) {
      float4 xv = xa[tok][i];
#pragma unroll
      for (int e = 0; e < 8; e++)
        acc[tok][e] = fmaf(xv.x, wv[e].x,
                      fmaf(xv.y, wv[e].y,
                      fmaf(xv.z, wv[e].z,
                      fmaf(xv.w, wv[e].w, acc[tok][e]))));
    }
  }

  float pi_acc[8] = {0, 0, 0, 0, 0, 0, 0, 0};
  float z_acc = 0.f;
#pragma unroll
  for (int tok = 0; tok < 2; tok++) {
    float a[8];
#pragma unroll
    for (int e = 0; e < 8; e++) a[e] = acc[tok][e];
#pragma unroll
    for (int off = 32; off > 0; off >>= 1)
#pragma unroll
      for (int e = 0; e < 8; e++) a[e] += __shfl_xor(a[e], off, 64);
    float mx = a[0]; int mi = 0;
#pragma unroll
    for (int e = 1; e < 8; e++) { if (a[e] > mx) { mx = a[e]; mi = e; } }
    float s = 0.f, pr[8];
#pragma unroll
    for (int e = 0; e < 8; e++) { pr[e] = __expf(a[e] - mx); s += pr[e]; }
    float inv = 1.f / s;
#pragma unroll
    for (int e = 0; e < 8; e++) pi_acc[e] += pr[e] * inv;
    float lse = mx + __logf(s);
    z_acc += lse * lse;
    if (lane == 0) { top_idx[t0 + tok] = mi; top_prob[t0 + tok] = pr[mi] * inv; }
  }

  if (lane == 0) {
#pragma unroll
    for (int e = 0; e < 8; e++) bstat[w][e] = pi_acc[e];
    bstat[w][8] = z_acc;
  }
  __syncthreads();
  if (tid < 9) {
    float s = bstat[0][tid] + bstat[1][tid] + bstat[2][tid] + bstat[3][tid];
    part[(size_t)blockIdx.x * 16 + tid] = s;
  }
}

// ---------------------------------------------------------------- FCFS scan (+stats reduce)
__global__ void __launch_bounds__(1024) scan_kernel(
    const int* __restrict__ top_idx, const float* __restrict__ part,
    int* __restrict__ dest_slot, int* __restrict__ src_token,
    float* __restrict__ aux_out) {
  __shared__ int cnt[1024 * 9];
  __shared__ float sstat[16][12];
  int tid = threadIdx.x;

  float ps[9];
#pragma unroll
  for (int e = 0; e < 9; e++) ps[e] = 0.f;
#pragma unroll
  for (int rr = 0; rr < 2; rr++) {
    const float* pp = &part[(size_t)(tid + rr * 1024) * 16];
#pragma unroll
    for (int e = 0; e < 9; e++) ps[e] += pp[e];
  }
#pragma unroll
  for (int off = 32; off > 0; off >>= 1)
#pragma unroll
    for (int e = 0; e < 9; e++) ps[e] += __shfl_xor(ps[e], off, 64);
  if ((tid & 63) == 0) {
#pragma unroll
    for (int e = 0; e < 9; e++) sstat[tid >> 6][e] = ps[e];
  }

  int eloc[16];
  int c[8] = {0, 0, 0, 0, 0, 0, 0, 0};
#pragma unroll
  for (int i = 0; i < 16; i++) {
    int e = top_idx[tid * 16 + i];
    eloc[i] = e;
    c[e]++;
  }
#pragma unroll
  for (int e = 0; e < 8; e++) cnt[tid * 9 + e] = c[e];
  __syncthreads();
  for (int s = 1; s < 1024; s <<= 1) {
    int v[8];
    if (tid >= s) {
#pragma unroll
      for (int e = 0; e < 8; e++) v[e] = cnt[(tid - s) * 9 + e];
    }
    __syncthreads();
    if (tid >= s) {
#pragma unroll
      for (int e = 0; e < 8; e++) cnt[tid * 9 + e] += v[e];
    }
    __syncthreads();
  }
  int run[8];
#pragma unroll
  for (int e = 0; e < 8; e++) run[e] = cnt[tid * 9 + e] - c[e];
#pragma unroll
  for (int i = 0; i < 16; i++) {
    int t = tid * 16 + i;
    int e = eloc[i];
    int pos = run[e]++;
    int d = (pos < CAP) ? (e * CAP + pos) : -1;
    dest_slot[t] = d;
    if (d >= 0) src_token[d] = t;
  }
  if (tid == 1023) {
    float st[9];
#pragma unroll
    for (int e = 0; e < 9; e++) {
      float s = 0.f;
      for (int ww = 0; ww < 16; ww++) s += sstat[ww][e];
      st[e] = s;
    }
    float aux = 0.f;
    for (int e = 0; e < 8; e++)
      aux += ((float)cnt[1023 * 9 + e] / (float)T_TOK) * (st[e] / (float)T_TOK);
    aux = 0.01f * 8.f * aux + 0.001f * (st[8] / (float)T_TOK);
    *aux_out = aux;
  }
}

// ---------------------------------------------------------------- dispatch + cast fp8
__global__ void __launch_bounds__(256) dispatch_kernel(
    const float* __restrict__ x, const int* __restrict__ src_token,
    unsigned char* __restrict__ A) {
  int slot = blockIdx.x;
  int tid = threadIdx.x;
  int src = src_token[slot];
  int v = 0;
  if (src >= 0) {
    float4 xv = *(const float4*)&x[(size_t)src * DM + tid * 4];
    v = pk4(xv.x, xv.y, xv.z, xv.w);
  }
  *(int*)&A[(size_t)slot * DM + tid * 4] = v;
}

// ---------------------------------------------------------------- transpose + cast fp8 (x64)
// src fp32 [E][K][N] -> dst fp8 [E][N][K], values scaled by 64 (HW scale 2^-6 undoes it)
__global__ void __launch_bounds__(256) transpose_cast_kernel(
    const float* __restrict__ src, unsigned char* __restrict__ dst,
    int K, int N) {
  __shared__ float tile[64][65];
  int e = blockIdx.z;
  int n0 = blockIdx.x * 64, k0 = blockIdx.y * 64;
  int tid = threadIdx.x;
  int tx = tid & 63, ty = tid >> 6;
  const float* S = src + (size_t)e * K * N;
  unsigned char* D = dst + (size_t)e * N * K;
#pragma unroll
  for (int r = 0; r < 16; r++) {
    int k = ty + r * 4;
    tile[k][tx] = S[(size_t)(k0 + k) * N + n0 + tx];
  }
  __syncthreads();
  int n = tid >> 2, kq = (tid & 3) * 16;
  int4 ov;
  int w[4];
#pragma unroll
  for (int g = 0; g < 4; g++) {
    int kk = kq + g * 4;
    w[g] = pk4(tile[kk + 0][n] * 64.f, tile[kk + 1][n] * 64.f,
               tile[kk + 2][n] * 64.f, tile[kk + 3][n] * 64.f);
  }
  ov.x = w[0]; ov.y = w[1]; ov.z = w[2]; ov.w = w[3];
  *(int4*)&D[(size_t)(n0 + n) * K + k0 + kq] = ov;
}

// LDS chunk swizzle: 128-byte rows of 8x16B chunks; data chunk cc stored at cc ^ (row&7)
// -> fragment reads hit 2 lanes/bank (free), staging stays within one 128B segment/row.

// ---------------------------------------------------------------- GEMM1: H = relu(A @ w1 + b1) fp8 out
// 256x256 tile, 8 waves (2Mx4N), BK=128B, DOUBLE-buffered LDS (128 KiB),
// T3 minimum-2-phase: stage(next) -> compute(cur) -> vmcnt(0) -> barrier -> flip.
// A fp8 [E*CAP][DM], BT=W1T fp8x64 [E][DF][DM]
__global__ void __launch_bounds__(512, 2) gemm1_kernel(
    const unsigned char* __restrict__ A, const unsigned char* __restrict__ BT,
    const float* __restrict__ b1, unsigned char* __restrict__ H) {
  __shared__ __align__(16) unsigned char As_[2][256 * 128];
  __shared__ __align__(16) unsigned char Bs_[2][256 * 128];
  int e = blockIdx.z;
  // bijective XCD swizzle within the 16x8 per-expert plane (128 blocks, %8==0)
  int plane = blockIdx.x + 16 * blockIdx.y;
  int nid = (plane & 7) * 16 + (plane >> 3);
  int n0 = (nid & 15) * 256, m0 = (nid >> 4) * 256;
  const unsigned char* Ae = A + ((size_t)e * CAP + m0) * DM;
  const unsigned char* Be = BT + ((size_t)e * DF + n0) * DM;
  int tid = threadIdx.x;
  int lane = tid & 63, wid = tid >> 6;
  int wmi = wid >> 2, wni = wid & 3;   // wave -> 128x64 output subtile
  int l15 = lane & 15, q = lane >> 4;
  floatx4 acc[8][4];
#pragma unroll
  for (int i = 0; i < 8; i++)
#pragma unroll
    for (int j = 0; j < 4; j++) acc[i][j] = (floatx4){0.f, 0.f, 0.f, 0.f};

  const int NT = DM / 128;  // 8
  // prologue: stage tile 0
#pragma unroll
  for (int r = 0; r < 4; r++) {
    int c = tid + 512 * r;
    int row = c >> 3, cc = c & 7;
    int ccs = cc ^ (row & 7);
    async_cp16(Ae + (size_t)row * DM + 0 + ccs * 16, As_[0] + c * 16);
    async_cp16(Be + (size_t)row * DM + 0 + ccs * 16, Bs_[0] + c * 16);
  }
  drain_and_sync();

  int cur = 0;
  for (int t = 0; t < NT; t++) {
    if (t + 1 < NT) {
      int kb = (t + 1) * 128;
#pragma unroll
      for (int r = 0; r < 4; r++) {
        int c = tid + 512 * r;
        int row = c >> 3, cc = c & 7;
        int ccs = cc ^ (row & 7);
        async_cp16(Ae + (size_t)row * DM + kb + ccs * 16, As_[cur ^ 1] + c * 16);
        async_cp16(Be + (size_t)row * DM + kb + ccs * 16, Bs_[cur ^ 1] + c * 16);
      }
    }
    const unsigned char* Asc = As_[cur];
    const unsigned char* Bsc = Bs_[cur];
#pragma unroll
    for (int ph = 0; ph < 4; ph++) {
      const int Mh = ph >> 1, Nh = ph & 1;
      intx8 af[4], bf[2];
#pragma unroll
      for (int i = 0; i < 4; i++) {
        int row = wmi * 128 + (Mh * 4 + i) * 16 + l15;
        int sw = row & 7;
        int4 lo = *(const int4*)&Asc[row * 128 + ((2 * q) ^ sw) * 16];
        int4 hi = *(const int4*)&Asc[row * 128 + ((2 * q + 1) ^ sw) * 16];
        af[i] = (intx8){lo.x, lo.y, lo.z, lo.w, hi.x, hi.y, hi.z, hi.w};
      }
#pragma unroll
      for (int j = 0; j < 2; j++) {
        int row = wni * 64 + (Nh * 2 + j) * 16 + l15;
        int sw = row & 7;
        int4 lo = *(const int4*)&Bsc[row * 128 + ((2 * q) ^ sw) * 16];
        int4 hi = *(const int4*)&Bsc[row * 128 + ((2 * q + 1) ^ sw) * 16];
        bf[j] = (intx8){lo.x, lo.y, lo.z, lo.w, hi.x, hi.y, hi.z, hi.w};
      }
#pragma unroll
      for (int i = 0; i < 4; i++)
#pragma unroll
        for (int j = 0; j < 2; j++)
          acc[Mh * 4 + i][Nh * 2 + j] = __builtin_amdgcn_mfma_scale_f32_16x16x128_f8f6f4(
              bf[j], af[i], acc[Mh * 4 + i][Nh * 2 + j], 0, 0, 0, SCALE_W, 0, SCALE_ONE);
    }
    drain_and_sync();
    cur ^= 1;
  }
  // operand-swap => D: m = l15, n = q*4 + reg
  const float* b1e = b1 + e * DF;
#pragma unroll
  for (int i = 0; i < 8; i++) {
    int m = m0 + wmi * 128 + i * 16 + l15;
    unsigned char* hrow = H + ((size_t)e * CAP + m) * DF;
#pragma unroll
    for (int j = 0; j < 4; j++) {
      int nb = n0 + wni * 64 + j * 16 + q * 4;
      float4 bv = *(const float4*)&b1e[nb];
      floatx4 a = acc[i][j];
      *(int*)&hrow[nb] = pk4(fmaxf(a[0] + bv.x, 0.f), fmaxf(a[1] + bv.y, 0.f),
                             fmaxf(a[2] + bv.z, 0.f), fmaxf(a[3] + bv.w, 0.f));
    }
  }
}

// ---------------------------------------------------------------- GEMM2: out[t] = p*(H @ w2 + b2)
// same 256x256 double-buffered schedule; Hm fp8 [E][CAP][DF], BT=W2T fp8x64 [E][DM][DF]
__global__ void __launch_bounds__(512, 2) gemm2_kernel(
    const unsigned char* __restrict__ Hm, const unsigned char* __restrict__ BT,
    const float* __restrict__ b2, const int* __restrict__ src_token,
    const float* __restrict__ top_prob, float* __restrict__ out) {
  __shared__ __align__(16) unsigned char As_[2][256 * 128];
  __shared__ __align__(16) unsigned char Bs_[2][256 * 128];
  int e = blockIdx.z;
  // bijective XCD swizzle within the 4x8 per-expert plane (32 blocks, %8==0)
  int plane = blockIdx.x + 4 * blockIdx.y;
  int nid = (plane & 7) * 4 + (plane >> 3);
  int n0 = (nid & 3) * 256, m0 = (nid >> 2) * 256;
  const unsigned char* Ae = Hm + ((size_t)e * CAP + m0) * DF;
  const unsigned char* Be = BT + ((size_t)e * DM + n0) * DF;
  int tid = threadIdx.x;
  int lane = tid & 63, wid = tid >> 6;
  int wmi = wid >> 2, wni = wid & 3;
  int l15 = lane & 15, q = lane >> 4;
  floatx4 acc[8][4];
#pragma unroll
  for (int i = 0; i < 8; i++)
#pragma unroll
    for (int j = 0; j < 4; j++) acc[i][j] = (floatx4){0.f, 0.f, 0.f, 0.f};

  const int NT = DF / 128;  // 32
#pragma unroll
  for (int r = 0; r < 4; r++) {
    int c = tid + 512 * r;
    int row = c >> 3, cc = c & 7;
    int ccs = cc ^ (row & 7);
    async_cp16(Ae + (size_t)row * DF + 0 + ccs * 16, As_[0] + c * 16);
    async_cp16(Be + (size_t)row * DF + 0 + ccs * 16, Bs_[0] + c * 16);
  }
  drain_and_sync();

  int cur = 0;
  for (int t = 0; t < NT; t++) {
    if (t + 1 < NT) {
      int kb = (t + 1) * 128;
#pragma unroll
      for (int r = 0; r < 4; r++) {
        int c = tid + 512 * r;
        int row = c >> 3, cc = c & 7;
        int ccs = cc ^ (row & 7);
        async_cp16(Ae + (size_t)row * DF + kb + ccs * 16, As_[cur ^ 1] + c * 16);
        async_cp16(Be + (size_t)row * DF + kb + ccs * 16, Bs_[cur ^ 1] + c * 16);
      }
    }
    const unsigned char* Asc = As_[cur];
    const unsigned char* Bsc = Bs_[cur];
#pragma unroll
    for (int ph = 0; ph < 4; ph++) {
      const int Mh = ph >> 1, Nh = ph & 1;
      intx8 af[4], bf[2];
#pragma unroll
      for (int i = 0; i < 4; i++) {
        int row = wmi * 128 + (Mh * 4 + i) * 16 + l15;
        int sw = row & 7;
        int4 lo = *(const int4*)&Asc[row * 128 + ((2 * q) ^ sw) * 16];
        int4 hi = *(const int4*)&Asc[row * 128 + ((2 * q + 1) ^ sw) * 16];
        af[i] = (intx8){lo.x, lo.y, lo.z, lo.w, hi.x, hi.y, hi.z, hi.w};
      }
#pragma unroll
      for (int j = 0; j < 2; j++) {
        int row = wni * 64 + (Nh * 2 + j) * 16 + l15;
        int sw = row & 7;
        int4 lo = *(const int4*)&Bsc[row * 128 + ((2 * q) ^ sw) * 16];
        int4 hi = *(const int4*)&Bsc[row * 128 + ((2 * q + 1) ^ sw) * 16];
        bf[j] = (intx8){lo.x, lo.y, lo.z, lo.w, hi.x, hi.y, hi.z, hi.w};
      }
#pragma unroll
      for (int i = 0; i < 4; i++)
#pragma unroll
        for (int j = 0; j < 2; j++)
          acc[Mh * 4 + i][Nh * 2 + j] = __builtin_amdgcn_mfma_scale_f32_16x16x128_f8f6f4(
              bf[j], af[i], acc[Mh * 4 + i][Nh * 2 + j], 0, 0, 0, SCALE_W, 0, SCALE_ONE);
    }
    drain_and_sync();
    cur ^= 1;
  }
  const float* b2e = b2 + e * DM;
#pragma unroll
  for (int i = 0; i < 8; i++) {
    int m = m0 + wmi * 128 + i * 16 + l15;
    int t = src_token[e * CAP + m];
    if (t < 0) continue;
    float p = top_prob[t];
    float* orow = out + (size_t)t * DM;
#pragma unroll
    for (int j = 0; j < 4; j++) {
      int nb = n0 + wni * 64 + j * 16 + q * 4;
      float4 bv = *(const float4*)&b2e[nb];
      floatx4 a = acc[i][j];
      float4 o;
      o.x = p * (a[0] + bv.x);
      o.y = p * (a[1] + bv.y);
      o.z = p * (a[2] + bv.z);
      o.w = p * (a[3] + bv.w);
      *(float4*)&orow[nb] = o;
    }
  }
}

// ---------------------------------------------------------------- dropped-token passthrough
__global__ void __launch_bounds__(256) passthru_kernel(
    const float* __restrict__ x, const int* __restrict__ dest_slot,
    float* __restrict__ out) {
  int t = blockIdx.x;
  if (dest_slot[t] >= 0) return;
  int c = threadIdx.x * 4;
  *(float4*)&out[(size_t)t * DM + c] = *(const float4*)&x[(size_t)t * DM + c];
}

// ---------------------------------------------------------------- launch
extern "C" void kernel_launch(void* const* d_in, const int* in_sizes, int n_in,
                              void* d_out, int out_size, void* d_ws, size_t ws_size,
                              hipStream_t stream) {
  const float* x  = (const float*)d_in[0];
  const float* wr = (const float*)d_in[1];
  const float* w1 = (const float*)d_in[2];
  const float* b1 = (const float*)d_in[3];
  const float* w2 = (const float*)d_in[4];
  const float* b2 = (const float*)d_in[5];
  float* out = (float*)d_out;

  // workspace layout (bytes)
  const size_t OFF_A    = 0;             // 16,777,216  A fp8 [E*CAP][DM]; router partials live here first
  const size_t OFF_W1T  = 16777216;      // 33,554,432  W1T fp8 [E][DF][DM]
  const size_t OFF_W2T  = 50331648;      // 33,554,432  W2T fp8 [E][DM][DF]
  const size_t OFF_H    = 83886080;      // 67,108,864  H fp8 [E][CAP][DF]
  const size_t OFF_TIDX = 150994944;
  const size_t OFF_TPRB = 151060480;
  const size_t OFF_DEST = 151126016;
  const size_t OFF_SRC  = 151191552;
  const size_t OFF_STAT = 151257088;
  if (ws_size < OFF_STAT + 64) return;

  char* ws = (char*)d_ws;
  unsigned char* A_f8 = (unsigned char*)(ws + OFF_A);
  float* part = (float*)(ws + OFF_A);    // 2048 blocks x 16 floats = 128 KB, consumed by scan before dispatch overwrites
  unsigned char* W1T  = (unsigned char*)(ws + OFF_W1T);
  unsigned char* W2T  = (unsigned char*)(ws + OFF_W2T);
  unsigned char* Hbuf = (unsigned char*)(ws + OFF_H);
  int*   top_idx   = (int*)(ws + OFF_TIDX);
  float* top_prob  = (float*)(ws + OFF_TPRB);
  int*   dest_slot = (int*)(ws + OFF_DEST);
  int*   src_token = (int*)(ws + OFF_SRC);

  hipLaunchKernelGGL(init_kernel, dim3(64), dim3(256), 0, stream, src_token);
  hipLaunchKernelGGL(router_kernel, dim3(2048), dim3(256), 0, stream,
                     x, wr, top_idx, top_prob, part);
  hipLaunchKernelGGL(scan_kernel, dim3(1), dim3(1024), 0, stream,
                     top_idx, part, dest_slot, src_token, out + (size_t)T_TOK * DM);
  hipLaunchKernelGGL(dispatch_kernel, dim3(NE * CAP), dim3(256), 0, stream,
                     x, src_token, A_f8);
  hipLaunchKernelGGL(transpose_cast_kernel, dim3(DF / 64, DM / 64, NE), dim3(256), 0, stream,
                     w1, W1T, DM, DF);
  hipLaunchKernelGGL(transpose_cast_kernel, dim3(DM / 64, DF / 64, NE), dim3(256), 0, stream,
                     w2, W2T, DF, DM);
  hipLaunchKernelGGL(gemm1_kernel, dim3(DF / 256, CAP / 256, NE), dim3(512), 0, stream,
                     A_f8, W1T, b1, Hbuf);
  hipLaunchKernelGGL(gemm2_kernel, dim3(DM / 256, CAP / 256, NE), dim3(512), 0, stream,
                     Hbuf, W2T, b2, src_token, top_prob, out);
  hipLaunchKernelGGL(passthru_kernel, dim3(T_TOK), dim3(256), 0, stream,
                     x, dest_slot, out);
}